// Round 1
// 682.906 us; speedup vs baseline: 1.1152x; 1.1152x over previous
//
#include <hip/hip_runtime.h>
#include <stdint.h>
#include <stddef.h>

// Problem constants (fixed by reference: B=8, T=4000)
#define NTOK   32000      // B*T
#define HID    1024
#define NQKV   3072
#define CTX    200
#define NH     16

typedef _Float16 f16;
typedef _Float16 f16x8 __attribute__((ext_vector_type(8)));
typedef _Float16 f16x4 __attribute__((ext_vector_type(4)));
typedef float    f32x4 __attribute__((ext_vector_type(4)));

__device__ __forceinline__ void async_copy16(const void* g, void* l) {
  typedef const __attribute__((address_space(1))) char gchar;
  typedef __attribute__((address_space(3))) char lchar;
  __builtin_amdgcn_global_load_lds((gchar*)g, (lchar*)l, 16, 0, 0);
}

// ---------------------------------------------------------------------------
// prep: wt_qkv[n][k] = [wq|wkv]^T as f16 ; wt_o[n][k] = wo^T ; rel -> f16
// ---------------------------------------------------------------------------
__global__ __launch_bounds__(256) void prep_kernel(
    const float* __restrict__ wq, const float* __restrict__ wkv,
    const float* __restrict__ wo, const float* __restrict__ rel,
    f16* __restrict__ wt_qkv, f16* __restrict__ wt_o, f16* __restrict__ rel_h) {
  long idx = (long)blockIdx.x * 256 + threadIdx.x;
  if (idx < (long)NQKV * HID) {
    int n = (int)(idx >> 10), k = (int)(idx & 1023);
    float v = (n < 1024) ? wq[(size_t)k * 1024 + n] : wkv[(size_t)k * 2048 + (n - 1024)];
    wt_qkv[idx] = (f16)v;
    return;
  }
  idx -= (long)NQKV * HID;
  if (idx < (long)HID * HID) {
    int n = (int)(idx >> 10), k = (int)(idx & 1023);
    wt_o[idx] = (f16)wo[(size_t)k * 1024 + n];
    return;
  }
  idx -= (long)HID * HID;
  if (idx < 1025 * 64) rel_h[idx] = (f16)rel[idx];
}

// ---------------------------------------------------------------------------
// LayerNorm: one block per token, 256 threads * float4, fp32 reduce -> f16 x
// ---------------------------------------------------------------------------
__global__ __launch_bounds__(256) void ln_kernel(
    const float* __restrict__ hs, const float* __restrict__ lw,
    const float* __restrict__ lb, f16* __restrict__ x) {
  int tok = blockIdx.x;
  int t = threadIdx.x;
  const float4* src = (const float4*)(hs + (size_t)tok * HID);
  float4 v = src[t];
  float s  = v.x + v.y + v.z + v.w;
  float s2 = v.x * v.x + v.y * v.y + v.z * v.z + v.w * v.w;
  for (int m = 1; m < 64; m <<= 1) { s += __shfl_xor(s, m); s2 += __shfl_xor(s2, m); }
  __shared__ float ps[4], ps2[4];
  int w = t >> 6;
  if ((t & 63) == 0) { ps[w] = s; ps2[w] = s2; }
  __syncthreads();
  s  = ps[0] + ps[1] + ps[2] + ps[3];
  s2 = ps2[0] + ps2[1] + ps2[2] + ps2[3];
  float mu  = s * (1.0f / 1024.0f);
  float var = s2 * (1.0f / 1024.0f) - mu * mu;
  float rs  = rsqrtf(var + 1e-5f);
  float4 wv = ((const float4*)lw)[t];
  float4 bv = ((const float4*)lb)[t];
  f16x4 o;
  o[0] = (f16)((v.x - mu) * rs * wv.x + bv.x);
  o[1] = (f16)((v.y - mu) * rs * wv.y + bv.y);
  o[2] = (f16)((v.z - mu) * rs * wv.z + bv.z);
  o[3] = (f16)((v.w - mu) * rs * wv.w + bv.w);
  *(f16x4*)(x + (size_t)tok * HID + t * 4) = o;
}

// ---------------------------------------------------------------------------
// GEMM: C[M,N] = A[M,1024] @ Bt[N,1024]^T, fp16 in / fp32 acc.
// 256x256 tile, BK=64, 512 threads (8 waves, 2Mx4N), 128 KiB LDS double-buffer.
// 8-phase schedule (T3+T4): per phase {ds_read subtile | stage 1 half-tile via
// global_load_lds | barrier | lgkmcnt(0) | setprio(1) 16xMFMA setprio(0) |
// barrier}; counted s_waitcnt vmcnt(6) ONLY at phases 4 and 8 (loads stay in
// flight across barriers). Granule swizzle (g ^= row&7, 8x16B per 128B row)
// applied on the global source side (global_load_lds dest must be linear) and
// on the ds_read side -> conflict-free ds_read_b128.
// Final iteration re-stages K-tiles 14/15 (identical data, clamped index) so
// vmcnt bookkeeping stays in steady state.
// EPI==0: store f16 to BLOCKED qkv layout [bn][h][sel][200][64].
// EPI==1: store f32 + bias, row-major.
// ---------------------------------------------------------------------------
template <int EPI>
__global__ __launch_bounds__(512, 2) void gemm_kernel(
    const f16* __restrict__ A, const f16* __restrict__ Bt,
    void* __restrict__ C, const float* __restrict__ bias, int N) {
  // [0]=A buf0, [1]=B buf0, [2]=A buf1, [3]=B buf1; each 256 rows x 64 f16
  __shared__ __attribute__((aligned(16))) f16 sm[4][16384];   // 128 KiB

  int t = threadIdx.x;
  int w = t >> 6, l = t & 63;
  int wm = w >> 2, wn = w & 3;          // 2 x 4 wave grid
  int lr = l & 15, lk = l >> 4;
  int sw = lr & 7;
  // staging: lane l covers row (l>>3) of its 8-row group; global granule
  // pre-swizzled so linear LDS write yields phys_granule = logical ^ (row&7)
  const int sg_off = ((l >> 3) << 10) + (((l & 7) ^ (l >> 3)) << 3);

  // XCD-aware bijective block swizzle (nwg % 8 != 0 -> m204 variant)
  int nwg = (int)(gridDim.x * gridDim.y);
  int lid = (int)(blockIdx.y * gridDim.x + blockIdx.x);
  int q = nwg >> 3, r = nwg & 7;
  int xcd = lid & 7, loc = lid >> 3;
  int nid = (xcd < r ? xcd * (q + 1) : r * (q + 1) + (xcd - r) * q) + loc;
  int bx = nid % (int)gridDim.x, by = nid / (int)gridDim.x;
  const int m0 = by * 256, n0 = bx * 256;

  f32x4 acc[8][4] = {};
  f16x8 a[8], b[8];

#define STG(reg, half, gsrc, row0, kt) do {                                        \
    const f16* _s = (gsrc) + (size_t)((row0) + (half) * 128 + w * 16) * 1024       \
                    + (kt) * 64 + sg_off;                                          \
    char* _d = (char*)(reg) + (half) * 16384 + w * 2048;                           \
    async_copy16(_s, _d);                                                          \
    async_copy16(_s + 8 * 1024, _d + 1024);                                        \
  } while (0)

#define LDA(As_, Mh) do {                                                          \
    _Pragma("unroll") for (int mt = 0; mt < 4; ++mt) {                             \
      int row_ = wm * 128 + (Mh) * 64 + mt * 16 + lr;                              \
      _Pragma("unroll") for (int ks = 0; ks < 2; ++ks)                             \
        a[mt * 2 + ks] = *(const f16x8*)((As_) + row_ * 64                         \
                          + (((ks * 4 + lk) ^ sw) << 3));                          \
    } } while (0)

#define LDB(Bs_, Nh) do {                                                          \
    _Pragma("unroll") for (int nt = 0; nt < 2; ++nt) {                             \
      int row_ = wn * 64 + (Nh) * 32 + nt * 16 + lr;                               \
      _Pragma("unroll") for (int ks = 0; ks < 2; ++ks)                             \
        b[(Nh) * 4 + nt * 2 + ks] = *(const f16x8*)((Bs_) + row_ * 64              \
                          + (((ks * 4 + lk) ^ sw) << 3));                          \
    } } while (0)

#define MMA(Mh, Nh) do {                                                           \
    __builtin_amdgcn_s_setprio(1);                                                 \
    _Pragma("unroll") for (int mt = 0; mt < 4; ++mt)                               \
    _Pragma("unroll") for (int nt = 0; nt < 2; ++nt)                               \
    _Pragma("unroll") for (int ks = 0; ks < 2; ++ks)                               \
      acc[(Mh) * 4 + mt][(Nh) * 2 + nt] = __builtin_amdgcn_mfma_f32_16x16x32_f16(  \
          a[mt * 2 + ks], b[(Nh) * 4 + nt * 2 + ks],                               \
          acc[(Mh) * 4 + mt][(Nh) * 2 + nt], 0, 0, 0);                             \
    __builtin_amdgcn_s_setprio(0); } while (0)

#define BAR  __builtin_amdgcn_s_barrier()
#define WLG  asm volatile("s_waitcnt lgkmcnt(0)" ::: "memory")
#define WVM6 asm volatile("s_waitcnt vmcnt(6)" ::: "memory")

  // ---- prologue: Kt0 -> buf0 (B0,B1,A0,A1); Kt1 -> buf1 (B0,B1,A0)
  STG(sm[1], 0, Bt, n0, 0);
  STG(sm[1], 1, Bt, n0, 0);
  STG(sm[0], 0, A, m0, 0);
  STG(sm[0], 1, A, m0, 0);
  asm volatile("s_waitcnt vmcnt(4)" ::: "memory");
  STG(sm[3], 0, Bt, n0, 1);
  STG(sm[3], 1, Bt, n0, 1);
  STG(sm[2], 0, A, m0, 1);
  WVM6;            // Kt0 fully landed (14 issued, <=6 outstanding)
  BAR;

  for (int j = 0; j < 8; ++j) {
    int k1 = 2 * j + 1;                              // completes buf1's K-tile
    int ke = (2 * j + 2 > 14) ? 14 : 2 * j + 2;      // -> buf0 (clamped restage)
    int ko = (2 * j + 3 > 15) ? 15 : 2 * j + 3;      // -> buf1 (clamped restage)
    // ---- K-tile 2j from buf0 ----
    // P1
    LDA(sm[0], 0); LDB(sm[1], 0);
    STG(sm[2], 1, A, m0, k1);
    BAR; WLG; MMA(0, 0); BAR;
    // P2
    LDB(sm[1], 1);
    STG(sm[1], 0, Bt, n0, ke);
    BAR; WLG; MMA(0, 1); BAR;
    // P3
    LDA(sm[0], 1);
    STG(sm[1], 1, Bt, n0, ke);
    BAR; WLG; MMA(1, 0); BAR;
    // P4
    STG(sm[0], 0, A, m0, ke);
    BAR; MMA(1, 1); WVM6; BAR;
    // ---- K-tile 2j+1 from buf1 ----
    // P5
    LDA(sm[2], 0); LDB(sm[3], 0);
    STG(sm[0], 1, A, m0, ke);
    BAR; WLG; MMA(0, 0); BAR;
    // P6
    LDB(sm[3], 1);
    STG(sm[3], 0, Bt, n0, ko);
    BAR; WLG; MMA(0, 1); BAR;
    // P7
    LDA(sm[2], 1);
    STG(sm[3], 1, Bt, n0, ko);
    BAR; WLG; MMA(1, 0); BAR;
    // P8
    STG(sm[2], 0, A, m0, ko);
    BAR; MMA(1, 1); WVM6; BAR;
  }

#undef STG
#undef LDA
#undef LDB
#undef MMA
#undef BAR
#undef WLG
#undef WVM6

  if constexpr (EPI == 0) {
    // blocked store: gcol -> (sel, h, d); grow -> (bn, io)
    #pragma unroll
    for (int mt = 0; mt < 8; ++mt) {
      #pragma unroll
      for (int rr = 0; rr < 4; ++rr) {
        int grow = m0 + wm * 128 + mt * 16 + lk * 4 + rr;
        unsigned bn = (unsigned)grow / 200u;
        unsigned io = (unsigned)grow - bn * 200u;
        size_t rowb = (size_t)bn * 614400 + (size_t)io * 64;
        #pragma unroll
        for (int nt = 0; nt < 4; ++nt) {
          int gcol = n0 + wn * 64 + nt * 16 + lr;
          int sel = gcol >> 10;
          int hh  = (gcol >> 6) & 15;
          int d   = gcol & 63;
          ((f16*)C)[rowb + (size_t)(hh * 3 + sel) * 12800 + d] = (f16)acc[mt][nt][rr];
        }
      }
    }
  } else {
    #pragma unroll
    for (int mt = 0; mt < 8; ++mt)
      #pragma unroll
      for (int nt = 0; nt < 4; ++nt) {
        int gcol = n0 + wn * 64 + nt * 16 + lr;
        float bv = bias[gcol];
        #pragma unroll
        for (int rr = 0; rr < 4; ++rr) {
          int grow = m0 + wm * 128 + mt * 16 + lk * 4 + rr;
          ((float*)C)[(size_t)grow * N + gcol] = acc[mt][nt][rr] + bv;
        }
      }
  }
}

// ---------------------------------------------------------------------------
// Block attention v3: one WG (4 waves) per (b, n, h); blocked qkv input.
// S^T = K.Q^T so softmaxed P lands in registers already in A-frag layout
// (K16 MFMA: k = 4*quad + reg) -> PV needs no LDS round trip for P.
//   - K staged once in LDS via global_load_lds, XOR-swizzled granules.
//   - V^T staged once in LDS [64][200].
//   - rel bias G^T[pp][i] = q_i . rel[313+m0+pp] via MFMA (rel rows from
//     global, L2-hot); through per-wave stride-17 LDS buf; gathered as
//     S^T[j][i] += G^T[i+199-j][i] (conflict-free scalar reads).
//   - O written via small LDS transpose -> full 128-B-line global stores.
// One barrier total; waves own whole 16-col chunks. LDS 81,464 B -> 2 WG/CU.
// ---------------------------------------------------------------------------
__global__ __launch_bounds__(256, 2) void attn_kernel(
    const f16* __restrict__ qkvb, const f16* __restrict__ rel_h,
    f16* __restrict__ out) {
  __shared__ __attribute__((aligned(16))) f16 Ks[208 * 64];     // 26,624 B
  __shared__ __attribute__((aligned(16))) f16 Vt[64 * 200];     // 25,600 B
  __shared__ __attribute__((aligned(16))) f16 Gb[4][215 * 17];  // 29,240 B

  int bh = blockIdx.x;
  int h  = bh & 15;
  size_t t0 = (size_t)(bh >> 4) * CTX;
  int t = threadIdx.x;
  int w = t >> 6, l = t & 63;
  int lr = l & 15, lk = l >> 4;

  const f16* Qb = qkvb + (size_t)bh * 38400;
  const f16* Kb = Qb + 12800;
  const f16* Vb = Qb + 25600;

  // ---- stage K, swizzled: phys granule pg holds logical pg ^ (row & 7)
  for (int it = w; it < 26; it += 4) {
    int srow = it * 8 + (l >> 3);
    int pg   = l & 7;
    int grow = srow < 200 ? srow : 199;   // pad rows: finite dup of row 199
    int gg   = pg ^ (srow & 7);
    async_copy16(Kb + (size_t)grow * 64 + gg * 8, (char*)Ks + it * 1024);
  }
  // ---- stage V^T: lane owns col d=l, wave handles j-quads w, w+4, ...
  {
    const f16* vcol = Vb + l;
    for (int g = w; g < 50; g += 4) {
      int j = g * 4;
      f16x4 pk;
      #pragma unroll
      for (int u = 0; u < 4; ++u) pk[u] = vcol[(size_t)(j + u) * 64];
      *(f16x4*)(Vt + l * 200 + j) = pk;
    }
  }
  __syncthreads();   // drains vmcnt (global_load_lds) + lgkm

  f16* gb = Gb[w];

  for (int c = w; c < 13; c += 4) {
    int m0 = c * 16;
    // ---- Q B-frags (pre-scaled by 1/8 = softmax scale, applies to QK & G)
    int qrow = m0 + lr; if (qrow > 199) qrow = 199;
    f16x8 bq0 = *(const f16x8*)(Qb + (size_t)qrow * 64 + lk * 8);
    f16x8 bq1 = *(const f16x8*)(Qb + (size_t)qrow * 64 + 32 + lk * 8);
    bq0 = bq0 * (f16)0.125f;
    bq1 = bq1 * (f16)0.125f;

    // ---- S^T[j][i]: A = K rows (LDS, swizzled), B = Q rows
    f32x4 S[13];
    #pragma unroll
    for (int ts = 0; ts < 13; ++ts) {
      int row = ts * 16 + lr;
      int sw  = row & 7;
      f16x8 a0 = *(const f16x8*)(Ks + row * 64 + (lk ^ sw) * 8);
      f16x8 a1 = *(const f16x8*)(Ks + row * 64 + ((4 + lk) ^ sw) * 8);
      f32x4 a = {};
      a = __builtin_amdgcn_mfma_f32_16x16x32_f16(a0, bq0, a, 0, 0, 0);
      S[ts] = __builtin_amdgcn_mfma_f32_16x16x32_f16(a1, bq1, a, 0, 0, 0);
    }

    // ---- G^T[pp][i]: A = rel rows (global, L2-hot), B = Q rows
    const f16* rb = rel_h + (size_t)(313 + m0) * 64;
    #pragma unroll
    for (int tg = 0; tg < 14; ++tg) {
      int pr = tg * 16 + lr;
      f16x8 a0 = *(const f16x8*)(rb + (size_t)pr * 64 + lk * 8);
      f16x8 a1 = *(const f16x8*)(rb + (size_t)pr * 64 + 32 + lk * 8);
      f32x4 g = {};
      g = __builtin_amdgcn_mfma_f32_16x16x32_f16(a0, bq0, g, 0, 0, 0);
      g = __builtin_amdgcn_mfma_f32_16x16x32_f16(a1, bq1, g, 0, 0, 0);
      #pragma unroll
      for (int r = 0; r < 4; ++r) {
        int pp2 = tg * 16 + 4 * lk + r;
        if (pp2 <= 214) gb[pp2 * 17 + lr] = (f16)g[r];
      }
    }

    // ---- gather: S^T[j][i] += G^T[i+199-j][i]
    #pragma unroll
    for (int ts = 0; ts < 13; ++ts) {
      #pragma unroll
      for (int r = 0; r < 4; ++r) {
        int pp = lr + 199 - ts * 16 - 4 * lk - r;
        if (pp < 0) pp = 0;   // only dead j (>=200) hit this
        S[ts][r] += (float)gb[pp * 17 + lr];
      }
    }
    // ---- mask dead j (tile 12, j = 192+4lk+r >= 200)
    #pragma unroll
    for (int r = 0; r < 4; ++r)
      if (4 * lk + r >= 8) S[12][r] = -1e30f;

    // ---- softmax over j (in-lane 52 values + lanes lr, lr+16, lr+32, lr+48)
    float mx = -1e30f;
    #pragma unroll
    for (int ts = 0; ts < 13; ++ts)
      #pragma unroll
      for (int r = 0; r < 4; ++r) mx = fmaxf(mx, S[ts][r]);
    mx = fmaxf(mx, __shfl_xor(mx, 16));
    mx = fmaxf(mx, __shfl_xor(mx, 32));
    float sum = 0.f;
    #pragma unroll
    for (int ts = 0; ts < 13; ++ts)
      #pragma unroll
      for (int r = 0; r < 4; ++r) {
        float e = __expf(S[ts][r] - mx);
        S[ts][r] = e;
        sum += e;
      }
    sum += __shfl_xor(sum, 16);
    sum += __shfl_xor(sum, 32);
    float inv = 1.0f / sum;

    // ---- P^T in registers == A-frags for K16 MFMA (k = 4*quad + reg)
    f16x4 P[13];
    #pragma unroll
    for (int ts = 0; ts < 13; ++ts)
      #pragma unroll
      for (int r = 0; r < 4; ++r) P[ts][r] = (f16)(S[ts][r] * inv);

    // ---- PV: D[i][d] = sum_j P[i][j] V^T[d][j], 4 d-tiles x 13 k-tiles
    f32x4 o[4] = {};
    #pragma unroll
    for (int ts = 0; ts < 13; ++ts) {
      int col4 = ts * 16 + 4 * lk;
      if (col4 > 196) col4 = 196;   // dead-k lanes only (P=0 there)
      #pragma unroll
      for (int dt = 0; dt < 4; ++dt) {
        f16x4 bv = *(const f16x4*)(Vt + (dt * 16 + lr) * 200 + col4);
        o[dt] = __builtin_amdgcn_mfma_f32_16x16x16f16(P[ts], bv, o[dt], 0, 0, 0);
      }
    }

    // ---- O via LDS transpose (reuse gb) -> full-line coalesced stores
    {
      f16* ob = gb;   // 16 x 72 f16 = 2304 B, fits in Gb[w]
      #pragma unroll
      for (int dt = 0; dt < 4; ++dt)
        #pragma unroll
        for (int r = 0; r < 4; ++r)
          ob[(4 * lk + r) * 72 + dt * 16 + lr] = (f16)o[dt][r];
      // read back row-major: lane l -> row l>>2, col quad (l&3)*16
      int orow = l >> 2;
      int ocol = (l & 3) * 16;
      if (m0 + orow < 200) {
        f16x8 v0 = *(const f16x8*)(ob + orow * 72 + ocol);
        f16x8 v1 = *(const f16x8*)(ob + orow * 72 + ocol + 8);
        f16* dst = out + (t0 + m0 + orow) * HID + h * 64 + ocol;
        *(f16x8*)dst = v0;
        *(f16x8*)(dst + 8) = v1;
      }
    }
  }
}

// ---------------------------------------------------------------------------
extern "C" void kernel_launch(void* const* d_in, const int* in_sizes, int n_in,
                              void* d_out, int out_size, void* d_ws, size_t ws_size,
                              hipStream_t stream) {
  const float* hs  = (const float*)d_in[0];
  const float* lnw = (const float*)d_in[1];
  const float* lnb = (const float*)d_in[2];
  const float* wq  = (const float*)d_in[3];
  const float* wkv = (const float*)d_in[4];
  const float* wo  = (const float*)d_in[5];
  const float* bo  = (const float*)d_in[6];
  const float* rel = (const float*)d_in[7];

  // workspace layout (bytes); total ~271 MB
  char* ws = (char*)d_ws;
  f16* x     = (f16*)(ws);                         // 32000*1024*2 = 65,536,000
  f16* qkvb  = (f16*)(ws + 65536000);              // 2560*38400*2 = 196,608,000
  f16* wtqkv = (f16*)(ws + 65536000 + 196608000);                  // 6,291,456
  f16* wto   = (f16*)(ws + 65536000 + 196608000 + 6291456);        // 2,097,152
  f16* rel_h = (f16*)(ws + 65536000 + 196608000 + 6291456 + 2097152); // 131,200
  f16* attn  = x;  // attention output aliases x (x dead after QKV GEMM)

  {
    long total = (long)NQKV * HID + (long)HID * HID + 1025 * 64;
    int grid = (int)((total + 255) / 256);
    prep_kernel<<<grid, 256, 0, stream>>>(wq, wkv, wo, rel, wtqkv, wto, rel_h);
  }
  ln_kernel<<<NTOK, 256, 0, stream>>>(hs, lnw, lnb, x);
  gemm_kernel<0><<<dim3(NQKV / 256, NTOK / 256), 512, 0, stream>>>(x, wtqkv, (void*)qkvb, nullptr, NQKV);
  attn_kernel<<<2560, 256, 0, stream>>>(qkvb, rel_h, attn);
  gemm_kernel<1><<<dim3(HID / 256, NTOK / 256), 512, 0, stream>>>(attn, wto, d_out, bo, HID);
}